// Round 7
// baseline (517.619 us; speedup 1.0000x reference)
//
#include <hip/hip_runtime.h>
#include <hip/hip_cooperative_groups.h>
#include <hip/hip_bf16.h>
#include <stdint.h>

namespace cg = cooperative_groups;

typedef unsigned short u16;
typedef __attribute__((ext_vector_type(8))) short short8;   // 8 x bf16 (4 VGPRs) MFMA A/B frag
typedef __attribute__((ext_vector_type(4))) float floatx4;  // MFMA C/D frag

#define BATCH 4
#define SEQ   2048
#define DIM   1024

__device__ inline u16 f2bf(float f) {
  union { float f; uint32_t u; } v; v.f = f;
  uint32_t r = v.u + 0x7fffu + ((v.u >> 16) & 1u);  // RNE
  return (u16)(r >> 16);
}

// packed fp32x2 -> bf16x2 (v_cvt_pk_bf16_f32 on gfx950), RNE — bit-identical to f2bf
__device__ inline uint32_t f2bf2(float lo, float hi) {
  __hip_bfloat162 h = __float22bfloat162_rn(float2{lo, hi});
  union { __hip_bfloat162 h; uint32_t u; } v; v.h = h;
  return v.u;
}

// async global->LDS, 16B per lane; LDS dest is wave-uniform base (+lane*16 by HW)
__device__ inline void gload_lds16(const u16* g, u16* l) {
  __builtin_amdgcn_global_load_lds((const __attribute__((address_space(1))) uint32_t*)g,
                                   (__attribute__((address_space(3))) uint32_t*)l,
                                   16, 0, 0);
}

// ---------------- fused prep: x->bf16, W->Wt bf16, bias gather, lsum zero ----------------
// blocks [0,8192): cvt x.  blocks [8192,11264): transpose W (32x32 tile each).
__global__ __launch_bounds__(256) void prep(const float* __restrict__ x,
                                            const float* __restrict__ Wq,
                                            const float* __restrict__ Wk,
                                            const float* __restrict__ Wv,
                                            const float* __restrict__ bq,
                                            const float* __restrict__ bk,
                                            const float* __restrict__ bv,
                                            u16* __restrict__ Xb,
                                            u16* __restrict__ Wt,
                                            float* __restrict__ bias,
                                            float* __restrict__ lsum) {
  __shared__ u16 tile[32][33];
  const int bx = blockIdx.x;
  if (bx < 8192) {
    size_t i = ((size_t)bx * 256 + threadIdx.x) * 4;
    float4 v = *(const float4*)(x + i);
    uint2 o;
    o.x = f2bf2(v.x, v.y);
    o.y = f2bf2(v.z, v.w);
    *(uint2*)(Xb + i) = o;
    if (bx < 8) {  // zero 8192 floats of lsum
      float4 z = {0.f, 0.f, 0.f, 0.f};
      *(float4*)(lsum + (size_t)bx * 1024 + threadIdx.x * 4) = z;
    }
    return;
  }
  const int t = bx - 8192;
  const int tz = t >> 10;            // 0..2  (weight index)
  const int bxx = t & 31;            // 32 col-tiles
  const int byy = (t >> 5) & 31;     // 32 row-tiles
  const float* W = (tz == 0) ? Wq : (tz == 1) ? Wk : Wv;
  u16* o = Wt + (size_t)tz * (1u << 20);
  if (bxx == 0 && byy == 0) {  // pack biases contiguously
    const float* bsrc = (tz == 0) ? bq : (tz == 1) ? bk : bv;
    float4 b4 = *(const float4*)(bsrc + threadIdx.x * 4);
    *(float4*)(bias + tz * 1024 + threadIdx.x * 4) = b4;
  }
  int c0 = bxx * 32, r0 = byy * 32;
  int tx = threadIdx.x & 31, ty = threadIdx.x >> 5;  // ty 0..7
#pragma unroll
  for (int p = 0; p < 4; ++p)
    tile[p * 8 + ty][tx] = f2bf(W[(size_t)(r0 + p * 8 + ty) * DIM + c0 + tx]);
  __syncthreads();
#pragma unroll
  for (int p = 0; p < 4; ++p)
    o[(size_t)(c0 + p * 8 + ty) * DIM + r0 + tx] = tile[tx][p * 8 + ty];
}

// LDS swizzle (both-sides, rule #21): slot s of row r holds source k-chunk s^((r>>1)&3).
// Staging: gload_lds dest stays linear; SOURCE chunk = (lane&3)^((lane>>3)&3).
// Read: chunk slot = (lane>>4)^((fr>>1)&3), fr=lane&15.  Verified 0 conflicts (r1-r6).

// ---------------- shared K-loop body (m97-class: BK=64, 2-barrier, gload_lds w=16) ----------------
template <int TM, int K>
__device__ __forceinline__ void kloop(const u16* __restrict__ Ab, const u16* __restrict__ Bb,
                                      u16* __restrict__ ldsA, u16* __restrict__ ldsB,
                                      int lane, int wave, floatx4 (&acc)[TM / 32][4]) {
  constexpr int MI = TM / 32;
  constexpr int AS = TM / 64;
  const int sr = lane >> 2;
  const int sc = ((lane & 3) ^ ((lane >> 3) & 3)) * 8;   // pre-swizzled source chunk
  const u16* gA0 = Ab + (size_t)(wave * (TM / 4) + sr) * K + sc;
  const u16* gB0 = Bb + (size_t)(wave * 32 + sr) * K + sc;
  u16* lA0 = ldsA + wave * (TM / 4) * 32;
  u16* lB0 = ldsB + wave * 1024;
  constexpr int SLA = TM * 32;
  constexpr int SLB = 4096;

  const int wm = (wave >> 1) * (TM / 2);
  const int wn = (wave & 1) * 64;
  const int fr = lane & 15;
  const int fk = ((lane >> 4) ^ ((fr >> 1) & 3)) * 8;    // swizzled read chunk
  const u16* la = ldsA + (wm + fr) * 32 + fk;
  const u16* lb = ldsB + (wn + fr) * 32 + fk;

  for (int kt = 0; kt < K; kt += 64) {
    __syncthreads();
#pragma unroll
    for (int i = 0; i < AS; ++i) {
      gload_lds16(gA0 + kt + (size_t)(16 * i) * K, lA0 + i * 512);
      gload_lds16(gA0 + kt + 32 + (size_t)(16 * i) * K, lA0 + SLA + i * 512);
    }
#pragma unroll
    for (int i = 0; i < 2; ++i) {
      gload_lds16(gB0 + kt + (size_t)(16 * i) * K, lB0 + i * 512);
      gload_lds16(gB0 + kt + 32 + (size_t)(16 * i) * K, lB0 + SLB + i * 512);
    }
    __syncthreads();
#pragma unroll
    for (int ks = 0; ks < 2; ++ks) {
      short8 a[MI], b[4];
#pragma unroll
      for (int i = 0; i < MI; ++i)
        a[i] = *(const short8*)(la + ks * SLA + i * 512);
#pragma unroll
      for (int i = 0; i < 4; ++i)
        b[i] = *(const short8*)(lb + ks * SLB + i * 512);
#pragma unroll
      for (int mi = 0; mi < MI; ++mi)
#pragma unroll
        for (int ni = 0; ni < 4; ++ni)
          acc[mi][ni] = __builtin_amdgcn_mfma_f32_16x16x32_bf16(a[mi], b[ni], acc[mi][ni], 0, 0, 0);
    }
  }
}

// ---------------- fused QKV+Vt projection, TM=128, BK=64 ----------------
// grid (64,8,3).  z in {0,1}: Q/K = Xb x Wt[z] + b, bf16 -> Q (+ 1/32 for z=0).
// z==2: Vt[b][h][s] = (Wv^T x^T + bv), column-demuxed store.
__global__ __launch_bounds__(256, 4)
void qkv_fused(const u16* __restrict__ Xb, const u16* __restrict__ Wt,
               u16* __restrict__ Q, u16* __restrict__ Vt,
               const float* __restrict__ bias) {
  constexpr int K = 1024;
  __shared__ u16 ldsA[128 * 64];
  __shared__ u16 ldsB[128 * 64];
  const int lane = threadIdx.x & 63;
  const int wave = threadIdx.x >> 6;
  const int z = blockIdx.z;

  int mt, nt, N;
  const u16 *Ab, *Bb;
  if (z < 2) {             // Q/K projection: A = Xb rows, B = Wt[z] rows
    mt = blockIdx.x; nt = blockIdx.y; N = 1024;
    Ab = Xb + (size_t)mt * 128 * K;
    Bb = Wt + (size_t)z * (1u << 20) + (size_t)nt * 128 * K;
  } else {                 // Vt projection: A = Wv^T rows (h), B = Xb rows (s)
    nt = blockIdx.x; mt = blockIdx.y; N = 8192;
    Ab = Wt + (size_t)2 * (1u << 20) + (size_t)mt * 128 * K;
    Bb = Xb + (size_t)nt * 128 * K;
  }

  floatx4 acc[4][4] = {};
  kloop<128, 1024>(Ab, Bb, ldsA, ldsB, lane, wave, acc);

  const int wm = (wave >> 1) * 64;
  const int wn = (wave & 1) * 64;
  const int er = (lane >> 4) * 4;
  const int ec = lane & 15;
  const int r0 = mt * 128 + wm;
  const int c0 = nt * 128 + wn;

  if (z < 2) {
    u16* C = Q + (size_t)z * (8u << 20);
    const float* bz = bias + z * 1024;
    const float zs = (z == 0) ? 0.03125f : 1.0f;  // fold 1/sqrt(1024) into Q
#pragma unroll
    for (int mi = 0; mi < 4; ++mi)
#pragma unroll
      for (int ni = 0; ni < 4; ++ni) {
        const int col = c0 + ni * 16 + ec;
        const float bb = bz[col];
        const int row = r0 + mi * 16 + er;
        const uint32_t p0 = f2bf2((acc[mi][ni][0] + bb) * zs, (acc[mi][ni][1] + bb) * zs);
        const uint32_t p1 = f2bf2((acc[mi][ni][2] + bb) * zs, (acc[mi][ni][3] + bb) * zs);
        C[(size_t)(row + 0) * N + col] = (u16)p0;
        C[(size_t)(row + 1) * N + col] = (u16)(p0 >> 16);
        C[(size_t)(row + 2) * N + col] = (u16)p1;
        C[(size_t)(row + 3) * N + col] = (u16)(p1 >> 16);
      }
  } else {
    const float* bz = bias + 2 * 1024;  // bv, indexed by row (=h)
#pragma unroll
    for (int mi = 0; mi < 4; ++mi) {
      float bb[4];
#pragma unroll
      for (int r = 0; r < 4; ++r) bb[r] = bz[r0 + mi * 16 + er + r];
#pragma unroll
      for (int ni = 0; ni < 4; ++ni) {
        const int col = c0 + ni * 16 + ec;
        const size_t base = (size_t)(col >> 11) * (1u << 21) + (col & 2047);
        const int row = r0 + mi * 16 + er;
        const uint32_t p0 = f2bf2(acc[mi][ni][0] + bb[0], acc[mi][ni][1] + bb[1]);
        const uint32_t p1 = f2bf2(acc[mi][ni][2] + bb[2], acc[mi][ni][3] + bb[3]);
        Vt[base + (size_t)(row + 0) * 2048] = (u16)p0;
        Vt[base + (size_t)(row + 1) * 2048] = (u16)(p0 >> 16);
        Vt[base + (size_t)(row + 2) * 2048] = (u16)p1;
        Vt[base + (size_t)(row + 3) * 2048] = (u16)(p1 >> 16);
      }
    }
  }
}

// ---------------- cooperative fused score+PV ----------------
// 1024 blocks (4 blk/CU; LDS 32KiB -> 5/CU cap, VGPR capped 128 by launch_bounds).
// Phase A: P~[z] = exp(Q K^T) tile (TM=128, K=1024), row sums -> lsum (atomics).
// grid.sync().  Phase B: out = (P~ Vt^T)/lsum tile (TM=64, K=2048).
// XCD-coordinated mapping: phase B's XCD c covers the SAME 512 P-rows phase A's c wrote
// (mt64 = 8*(c>>1)+.. vs mt128 = 4*(c>>1)+..) -> ~50% of P read hits local L2 (4MB/XCD, hot).
__global__ __launch_bounds__(256, 4)
void score_pv(const u16* __restrict__ Q, u16* __restrict__ P,
              const u16* __restrict__ Vt, float* __restrict__ out,
              float* __restrict__ lsum) {
  __shared__ u16 ldsA[128 * 64];
  __shared__ u16 ldsB[128 * 64];
  const int lane = threadIdx.x & 63;
  const int wave = threadIdx.x >> 6;
  const int bid = blockIdx.x;
  const int z = bid >> 8;            // batch
  const int q = bid & 255;
  const int c = q & 7, j = q >> 3;   // c = XCD slot, j in [0,32)
  const int er = (lane >> 4) * 4;
  const int ec = lane & 15;

  // ---------- phase A: score (TM=128) ----------
  {
    const int mt = 4 * (c >> 1) + (j & 3);       // 0..15
    const int nt = 8 * (c & 1) + (j >> 2);       // 0..15
    const u16* Ab = Q + (size_t)z * 2097152 + (size_t)mt * 128 * 1024;
    const u16* Bb = Q + 8388608 + (size_t)z * 2097152 + (size_t)nt * 128 * 1024;
    floatx4 acc[4][4] = {};
    kloop<128, 1024>(Ab, Bb, ldsA, ldsB, lane, wave, acc);

    const int wm = (wave >> 1) * 64;
    const int wn = (wave & 1) * 64;
    const int r0 = mt * 128 + wm;
    const int c0 = nt * 128 + wn;
    u16* C = P + (size_t)z * 4194304;
    float* lz = lsum + z * 2048;
#pragma unroll
    for (int mi = 0; mi < 4; ++mi) {
      float rs[4] = {0.f, 0.f, 0.f, 0.f};
#pragma unroll
      for (int ni = 0; ni < 4; ++ni) {
        const int col = c0 + ni * 16 + ec;
        const int row = r0 + mi * 16 + er;
        float e[4];
#pragma unroll
        for (int r = 0; r < 4; ++r) {
          e[r] = exp2f(acc[mi][ni][r] * 1.44269504088896340736f);
          rs[r] += e[r];
        }
        const uint32_t p0 = f2bf2(e[0], e[1]);
        const uint32_t p1 = f2bf2(e[2], e[3]);
        C[(size_t)(row + 0) * 2048 + col] = (u16)p0;
        C[(size_t)(row + 1) * 2048 + col] = (u16)(p0 >> 16);
        C[(size_t)(row + 2) * 2048 + col] = (u16)p1;
        C[(size_t)(row + 3) * 2048 + col] = (u16)(p1 >> 16);
      }
#pragma unroll
      for (int o = 1; o < 16; o <<= 1)
#pragma unroll
        for (int r = 0; r < 4; ++r) rs[r] += __shfl_xor(rs[r], o);
      if ((lane & 15) == 0) {
#pragma unroll
        for (int r = 0; r < 4; ++r)
          atomicAdd(&lz[r0 + mi * 16 + er + r], rs[r]);
      }
    }
  }

  __threadfence();                 // flush P stores to device scope
  cg::this_grid().sync();          // all P + lsum final

  // ---------- phase B: PV (TM=64, K=2048) ----------
  {
    const int mt = 8 * (c >> 1) + (j & 7);       // 0..31, same 512-row band as phase A
    const int nt = 4 * (c & 1) + (j >> 3);       // 0..7
    const u16* Ab = P + (size_t)z * 4194304 + (size_t)mt * 64 * 2048;
    const u16* Bb = Vt + (size_t)z * 2097152 + (size_t)nt * 128 * 2048;
    floatx4 acc[2][4] = {};
    kloop<64, 2048>(Ab, Bb, ldsA, ldsB, lane, wave, acc);

    const int wm = (wave >> 1) * 32;
    const int wn = (wave & 1) * 64;
    const int r0 = mt * 64 + wm;
    const int c0 = nt * 128 + wn;
    float* C = out + (size_t)z * 2097152;
    const float* lz = lsum + z * 2048;
#pragma unroll
    for (int mi = 0; mi < 2; ++mi) {
      float inv[4];
#pragma unroll
      for (int r = 0; r < 4; ++r) inv[r] = 1.0f / lz[r0 + mi * 16 + er + r];
#pragma unroll
      for (int ni = 0; ni < 4; ++ni) {
        const int col = c0 + ni * 16 + ec;
#pragma unroll
        for (int r = 0; r < 4; ++r) {
          const int row = r0 + mi * 16 + er + r;
          C[(size_t)row * 1024 + col] = acc[mi][ni][r] * inv[r];
        }
      }
    }
  }
}

// ---------------- fallback non-cooperative GEMM (r6 config), kept for safety ----------------
template <int EPI, int SWIZ, int TM>
__global__ __launch_bounds__(256, 4)
void gemm_bt(const u16* __restrict__ A, const u16* __restrict__ Bt,
             void* __restrict__ Cv, float* __restrict__ lsum,
             int M, int N, int K, size_t sA, size_t sB, size_t sC) {
  constexpr int MI = TM / 32;
  __shared__ u16 ldsA[TM * 64];
  __shared__ u16 ldsB[128 * 64];
  const int lane = threadIdx.x & 63;
  const int wave = threadIdx.x >> 6;

  int mt, nt;
  {
    const int lin = blockIdx.x;
    const int c = lin & 7, j = lin >> 3;
    if (SWIZ == 5) { mt = 4 * (c >> 1) + (j & 3); nt = 8 * (c & 1) + (j >> 2); }
    else           { mt = 8 * (c >> 1) + (j & 7); nt = 4 * (c & 1) + (j >> 3); }
  }

  const u16* Ab = A + sA * blockIdx.z + (size_t)mt * TM * K;
  const u16* Bb = Bt + sB * blockIdx.z + (size_t)nt * 128 * K;

  floatx4 acc[MI][4] = {};
  if (K == 1024) kloop<TM, 1024>(Ab, Bb, ldsA, ldsB, lane, wave, acc);
  else           kloop<TM, 2048>(Ab, Bb, ldsA, ldsB, lane, wave, acc);

  const int wm = (wave >> 1) * (TM / 2);
  const int wn = (wave & 1) * 64;
  const int er = (lane >> 4) * 4;
  const int ec = lane & 15;
  const int r0 = mt * TM + wm;
  const int c0 = nt * 128 + wn;

  if (EPI == 1) {
    u16* C = (u16*)Cv + sC * blockIdx.z;
    float* lz = lsum + blockIdx.z * 2048;
#pragma unroll
    for (int mi = 0; mi < MI; ++mi) {
      float rs[4] = {0.f, 0.f, 0.f, 0.f};
#pragma unroll
      for (int ni = 0; ni < 4; ++ni) {
        const int col = c0 + ni * 16 + ec;
        const int row = r0 + mi * 16 + er;
        float e[4];
#pragma unroll
        for (int r = 0; r < 4; ++r) {
          e[r] = exp2f(acc[mi][ni][r] * 1.44269504088896340736f);
          rs[r] += e[r];
        }
        const uint32_t p0 = f2bf2(e[0], e[1]);
        const uint32_t p1 = f2bf2(e[2], e[3]);
        C[(size_t)(row + 0) * N + col] = (u16)p0;
        C[(size_t)(row + 1) * N + col] = (u16)(p0 >> 16);
        C[(size_t)(row + 2) * N + col] = (u16)p1;
        C[(size_t)(row + 3) * N + col] = (u16)(p1 >> 16);
      }
#pragma unroll
      for (int o = 1; o < 16; o <<= 1)
#pragma unroll
        for (int r = 0; r < 4; ++r) rs[r] += __shfl_xor(rs[r], o);
      if ((lane & 15) == 0) {
#pragma unroll
        for (int r = 0; r < 4; ++r)
          atomicAdd(&lz[r0 + mi * 16 + er + r], rs[r]);
      }
    }
  } else {
    float* C = (float*)Cv + sC * blockIdx.z;
    const float* lz = lsum + blockIdx.z * 2048;
#pragma unroll
    for (int mi = 0; mi < MI; ++mi) {
      float inv[4];
#pragma unroll
      for (int r = 0; r < 4; ++r) inv[r] = 1.0f / lz[r0 + mi * 16 + er + r];
#pragma unroll
      for (int ni = 0; ni < 4; ++ni) {
        const int col = c0 + ni * 16 + ec;
#pragma unroll
        for (int r = 0; r < 4; ++r) {
          const int row = r0 + mi * 16 + er + r;
          C[(size_t)row * N + col] = acc[mi][ni][r] * inv[r];
        }
      }
    }
  }
}

extern "C" void kernel_launch(void* const* d_in, const int* in_sizes, int n_in,
                              void* d_out, int out_size, void* d_ws, size_t ws_size,
                              hipStream_t stream) {
  const float* x  = (const float*)d_in[0];
  const float* Wq = (const float*)d_in[1];
  const float* bq = (const float*)d_in[2];
  const float* Wk = (const float*)d_in[3];
  const float* bk = (const float*)d_in[4];
  const float* Wv = (const float*)d_in[5];
  const float* bv = (const float*)d_in[6];
  float* out = (float*)d_out;

  char* ws = (char*)d_ws;
  const size_t MB = 1ull << 20;
  u16* Q    = (u16*)(ws + 0 * MB);    // [2][8192][1024] bf16: Q,K contiguous
  u16* Kb   = (u16*)(ws + 16 * MB);
  u16* Vt   = (u16*)(ws + 48 * MB);   // [4][1024][2048]
  u16* Xb   = (u16*)(ws + 64 * MB);   // [8192][1024]
  u16* Wt   = (u16*)(ws + 80 * MB);   // [3][1024][1024]
  float* bias = (float*)(ws + 86 * MB);  // [3][1024]
  float* lsum = (float*)(ws + 87 * MB);  // [4][2048] softmax denominators
  u16* P    = (u16*)(ws + 88 * MB);   // [4][2048][2048] exp(scores), ends 120MB
  (void)Kb; (void)ws_size; (void)in_sizes; (void)n_in; (void)out_size;

  // 1) fused prep: x->bf16, W->Wt, bias gather, lsum zero
  prep<<<11264, 256, 0, stream>>>(x, Wq, Wk, Wv, bq, bk, bv, Xb, Wt, bias, lsum);
  // 2) fused QKV + Vt projection (Q pre-scaled by 1/32), TM=128, swizzled LDS
  qkv_fused<<<dim3(64, 8, 3), 256, 0, stream>>>(Xb, Wt, Q, Vt, bias);
  // 3+4) cooperative fused score+PV: one launch, grid.sync between phases.
  {
    const u16* Qa = Q; u16* Pa = P; const u16* Va = Vt; float* oa = out; float* la = lsum;
    void* args[] = {(void*)&Qa, (void*)&Pa, (void*)&Va, (void*)&oa, (void*)&la};
    hipError_t e = hipLaunchCooperativeKernel((const void*)score_pv, dim3(1024), dim3(256),
                                              args, 0, stream);
    if (e != hipSuccess) {  // fallback: r6's two-launch path
      gemm_bt<1, 5, 128><<<dim3(256, 1, 4), 256, 0, stream>>>(
          Q, Kb, P, lsum, 2048, 2048, 1024,
          (size_t)2097152, (size_t)2097152, (size_t)4194304);
      gemm_bt<2, 6, 64><<<dim3(256, 1, 4), 256, 0, stream>>>(
          P, Vt, out, lsum, 2048, 1024, 2048,
          (size_t)4194304, (size_t)2097152, (size_t)2097152);
    }
  }
}

// Round 8
// 273.941 us; speedup vs baseline: 1.8895x; 1.8895x over previous
//
#include <hip/hip_runtime.h>
#include <hip/hip_bf16.h>
#include <stdint.h>

typedef unsigned short u16;
typedef __attribute__((ext_vector_type(8))) short short8;   // 8 x bf16 (4 VGPRs) MFMA A/B frag
typedef __attribute__((ext_vector_type(4))) float floatx4;  // MFMA C/D frag

#define BATCH 4
#define SEQ   2048
#define DIM   1024

__device__ inline u16 f2bf(float f) {
  union { float f; uint32_t u; } v; v.f = f;
  uint32_t r = v.u + 0x7fffu + ((v.u >> 16) & 1u);  // RNE
  return (u16)(r >> 16);
}

// packed fp32x2 -> bf16x2 (v_cvt_pk_bf16_f32 on gfx950), RNE — bit-identical to f2bf
__device__ inline uint32_t f2bf2(float lo, float hi) {
  __hip_bfloat162 h = __float22bfloat162_rn(float2{lo, hi});
  union { __hip_bfloat162 h; uint32_t u; } v; v.h = h;
  return v.u;
}

// async global->LDS, 16B per lane; LDS dest is wave-uniform base (+lane*16 by HW)
__device__ inline void gload_lds16(const u16* g, u16* l) {
  __builtin_amdgcn_global_load_lds((const __attribute__((address_space(1))) uint32_t*)g,
                                   (__attribute__((address_space(3))) uint32_t*)l,
                                   16, 0, 0);
}

// ---------------- fused prep: x->bf16, W->Wt bf16, bias gather, lsum+out zero ----------------
// blocks [0,8192): cvt x.  [8192,11264): transpose W.  [11264,13312): zero out (for pv atomics).
__global__ __launch_bounds__(256) void prep(const float* __restrict__ x,
                                            const float* __restrict__ Wq,
                                            const float* __restrict__ Wk,
                                            const float* __restrict__ Wv,
                                            const float* __restrict__ bq,
                                            const float* __restrict__ bk,
                                            const float* __restrict__ bv,
                                            u16* __restrict__ Xb,
                                            u16* __restrict__ Wt,
                                            float* __restrict__ bias,
                                            float* __restrict__ lsum,
                                            float* __restrict__ out) {
  __shared__ u16 tile[32][33];
  const int bx = blockIdx.x;
  if (bx < 8192) {
    size_t i = ((size_t)bx * 256 + threadIdx.x) * 4;
    float4 v = *(const float4*)(x + i);
    uint2 o;
    o.x = f2bf2(v.x, v.y);
    o.y = f2bf2(v.z, v.w);
    *(uint2*)(Xb + i) = o;
    if (bx < 8) {  // zero 8192 floats of lsum
      float4 z = {0.f, 0.f, 0.f, 0.f};
      *(float4*)(lsum + (size_t)bx * 1024 + threadIdx.x * 4) = z;
    }
    return;
  }
  if (bx >= 11264) {  // zero out: 2048 blocks x 1024 float4 = 8.4M floats
    const int b2 = bx - 11264;
    const float4 z = {0.f, 0.f, 0.f, 0.f};
#pragma unroll
    for (int k = 0; k < 4; ++k)
      *(float4*)(out + ((size_t)b2 * 1024 + k * 256 + threadIdx.x) * 4) = z;
    return;
  }
  const int t = bx - 8192;
  const int tz = t >> 10;            // 0..2  (weight index)
  const int bxx = t & 31;            // 32 col-tiles
  const int byy = (t >> 5) & 31;     // 32 row-tiles
  const float* W = (tz == 0) ? Wq : (tz == 1) ? Wk : Wv;
  u16* o = Wt + (size_t)tz * (1u << 20);
  if (bxx == 0 && byy == 0) {  // pack biases contiguously
    const float* bsrc = (tz == 0) ? bq : (tz == 1) ? bk : bv;
    float4 b4 = *(const float4*)(bsrc + threadIdx.x * 4);
    *(float4*)(bias + tz * 1024 + threadIdx.x * 4) = b4;
  }
  int c0 = bxx * 32, r0 = byy * 32;
  int tx = threadIdx.x & 31, ty = threadIdx.x >> 5;  // ty 0..7
#pragma unroll
  for (int p = 0; p < 4; ++p)
    tile[p * 8 + ty][tx] = f2bf(W[(size_t)(r0 + p * 8 + ty) * DIM + c0 + tx]);
  __syncthreads();
#pragma unroll
  for (int p = 0; p < 4; ++p)
    o[(size_t)(c0 + p * 8 + ty) * DIM + r0 + tx] = tile[tx][p * 8 + ty];
}

// LDS swizzle (both-sides, rule #21): slot s of row r holds source k-chunk s^((r>>1)&3).
// Staging: gload_lds dest stays linear; SOURCE chunk = (lane&3)^((lane>>3)&3).
// Read: chunk slot = (lane>>4)^((fr>>1)&3), fr=lane&15.  Verified 0 conflicts (r1-r7).

// ---------------- shared K-loop body (m97-class: BK=64, 2-barrier, gload_lds w=16) ----------------
// LD = row stride (leading dim), KLEN = k extent of this block's slice.
template <int TM, int LD, int KLEN>
__device__ __forceinline__ void kloop(const u16* __restrict__ Ab, const u16* __restrict__ Bb,
                                      u16* __restrict__ ldsA, u16* __restrict__ ldsB,
                                      int lane, int wave, floatx4 (&acc)[TM / 32][4]) {
  constexpr int MI = TM / 32;
  constexpr int AS = TM / 64;
  const int sr = lane >> 2;
  const int sc = ((lane & 3) ^ ((lane >> 3) & 3)) * 8;   // pre-swizzled source chunk
  const u16* gA0 = Ab + (size_t)(wave * (TM / 4) + sr) * LD + sc;
  const u16* gB0 = Bb + (size_t)(wave * 32 + sr) * LD + sc;
  u16* lA0 = ldsA + wave * (TM / 4) * 32;
  u16* lB0 = ldsB + wave * 1024;
  constexpr int SLA = TM * 32;
  constexpr int SLB = 4096;

  const int wm = (wave >> 1) * (TM / 2);
  const int wn = (wave & 1) * 64;
  const int fr = lane & 15;
  const int fk = ((lane >> 4) ^ ((fr >> 1) & 3)) * 8;    // swizzled read chunk
  const u16* la = ldsA + (wm + fr) * 32 + fk;
  const u16* lb = ldsB + (wn + fr) * 32 + fk;

  for (int kt = 0; kt < KLEN; kt += 64) {
    __syncthreads();
#pragma unroll
    for (int i = 0; i < AS; ++i) {
      gload_lds16(gA0 + kt + (size_t)(16 * i) * LD, lA0 + i * 512);
      gload_lds16(gA0 + kt + 32 + (size_t)(16 * i) * LD, lA0 + SLA + i * 512);
    }
#pragma unroll
    for (int i = 0; i < 2; ++i) {
      gload_lds16(gB0 + kt + (size_t)(16 * i) * LD, lB0 + i * 512);
      gload_lds16(gB0 + kt + 32 + (size_t)(16 * i) * LD, lB0 + SLB + i * 512);
    }
    __syncthreads();
#pragma unroll
    for (int ks = 0; ks < 2; ++ks) {
      short8 a[MI], b[4];
#pragma unroll
      for (int i = 0; i < MI; ++i)
        a[i] = *(const short8*)(la + ks * SLA + i * 512);
#pragma unroll
      for (int i = 0; i < 4; ++i)
        b[i] = *(const short8*)(lb + ks * SLB + i * 512);
#pragma unroll
      for (int mi = 0; mi < MI; ++mi)
#pragma unroll
        for (int ni = 0; ni < 4; ++ni)
          acc[mi][ni] = __builtin_amdgcn_mfma_f32_16x16x32_bf16(a[mi], b[ni], acc[mi][ni], 0, 0, 0);
    }
  }
}

// ---------------- fused QKV+Vt projection, TM=128, BK=64 ----------------
// grid (64,8,3).  z in {0,1}: Q/K = Xb x Wt[z] + b, bf16 -> Q (+ 1/32 for z=0).
// z==2: Vt[b][h][s] = (Wv^T x^T + bv), column-demuxed store.
__global__ __launch_bounds__(256, 4)
void qkv_fused(const u16* __restrict__ Xb, const u16* __restrict__ Wt,
               u16* __restrict__ Q, u16* __restrict__ Vt,
               const float* __restrict__ bias) {
  __shared__ u16 ldsA[128 * 64];
  __shared__ u16 ldsB[128 * 64];
  const int lane = threadIdx.x & 63;
  const int wave = threadIdx.x >> 6;
  const int z = blockIdx.z;

  int mt, nt, N;
  const u16 *Ab, *Bb;
  if (z < 2) {             // Q/K projection: A = Xb rows, B = Wt[z] rows
    mt = blockIdx.x; nt = blockIdx.y; N = 1024;
    Ab = Xb + (size_t)mt * 128 * 1024;
    Bb = Wt + (size_t)z * (1u << 20) + (size_t)nt * 128 * 1024;
  } else {                 // Vt projection: A = Wv^T rows (h), B = Xb rows (s)
    nt = blockIdx.x; mt = blockIdx.y; N = 8192;
    Ab = Wt + (size_t)2 * (1u << 20) + (size_t)mt * 128 * 1024;
    Bb = Xb + (size_t)nt * 128 * 1024;
  }

  floatx4 acc[4][4] = {};
  kloop<128, 1024, 1024>(Ab, Bb, ldsA, ldsB, lane, wave, acc);

  const int wm = (wave >> 1) * 64;
  const int wn = (wave & 1) * 64;
  const int er = (lane >> 4) * 4;
  const int ec = lane & 15;
  const int r0 = mt * 128 + wm;
  const int c0 = nt * 128 + wn;

  if (z < 2) {
    u16* C = Q + (size_t)z * (8u << 20);
    const float* bz = bias + z * 1024;
    const float zs = (z == 0) ? 0.03125f : 1.0f;  // fold 1/sqrt(1024) into Q
#pragma unroll
    for (int mi = 0; mi < 4; ++mi)
#pragma unroll
      for (int ni = 0; ni < 4; ++ni) {
        const int col = c0 + ni * 16 + ec;
        const float bb = bz[col];
        const int row = r0 + mi * 16 + er;
        const uint32_t p0 = f2bf2((acc[mi][ni][0] + bb) * zs, (acc[mi][ni][1] + bb) * zs);
        const uint32_t p1 = f2bf2((acc[mi][ni][2] + bb) * zs, (acc[mi][ni][3] + bb) * zs);
        C[(size_t)(row + 0) * N + col] = (u16)p0;
        C[(size_t)(row + 1) * N + col] = (u16)(p0 >> 16);
        C[(size_t)(row + 2) * N + col] = (u16)p1;
        C[(size_t)(row + 3) * N + col] = (u16)(p1 >> 16);
      }
  } else {
    const float* bz = bias + 2 * 1024;  // bv, indexed by row (=h)
#pragma unroll
    for (int mi = 0; mi < 4; ++mi) {
      float bb[4];
#pragma unroll
      for (int r = 0; r < 4; ++r) bb[r] = bz[r0 + mi * 16 + er + r];
#pragma unroll
      for (int ni = 0; ni < 4; ++ni) {
        const int col = c0 + ni * 16 + ec;
        const size_t base = (size_t)(col >> 11) * (1u << 21) + (col & 2047);
        const int row = r0 + mi * 16 + er;
        const uint32_t p0 = f2bf2(acc[mi][ni][0] + bb[0], acc[mi][ni][1] + bb[1]);
        const uint32_t p1 = f2bf2(acc[mi][ni][2] + bb[2], acc[mi][ni][3] + bb[3]);
        Vt[base + (size_t)(row + 0) * 2048] = (u16)p0;
        Vt[base + (size_t)(row + 1) * 2048] = (u16)(p0 >> 16);
        Vt[base + (size_t)(row + 2) * 2048] = (u16)p1;
        Vt[base + (size_t)(row + 3) * 2048] = (u16)(p1 >> 16);
      }
    }
  }
}

// ---------------- P~ = exp(Q K^T), TM=128, grid (256,1,4) = 4 blk/CU ----------------
// XCD map: c = x&7, 4mt x 8... (16m x 16n per z; 4m x 4n... nt span 8*(c&1)+j>>2 -> 2x8? see r6)
__global__ __launch_bounds__(256, 4)
void score_k(const u16* __restrict__ Q, u16* __restrict__ P, float* __restrict__ lsum) {
  __shared__ u16 ldsA[128 * 64];
  __shared__ u16 ldsB[128 * 64];
  const int lane = threadIdx.x & 63;
  const int wave = threadIdx.x >> 6;
  const int z = blockIdx.z;
  const int c = blockIdx.x & 7, j = blockIdx.x >> 3;
  const int mt = 4 * (c >> 1) + (j & 3);       // 0..15
  const int nt = 8 * (c & 1) + (j >> 2);       // 0..15
  const u16* Ab = Q + (size_t)z * 2097152 + (size_t)mt * 128 * 1024;
  const u16* Bb = Q + 8388608 + (size_t)z * 2097152 + (size_t)nt * 128 * 1024;

  floatx4 acc[4][4] = {};
  kloop<128, 1024, 1024>(Ab, Bb, ldsA, ldsB, lane, wave, acc);

  const int wm = (wave >> 1) * 64;
  const int wn = (wave & 1) * 64;
  const int er = (lane >> 4) * 4;
  const int ec = lane & 15;
  const int r0 = mt * 128 + wm;
  const int c0 = nt * 128 + wn;
  u16* C = P + (size_t)z * 4194304;
  float* lz = lsum + z * 2048;
#pragma unroll
  for (int mi = 0; mi < 4; ++mi) {
    float rs[4] = {0.f, 0.f, 0.f, 0.f};
#pragma unroll
    for (int ni = 0; ni < 4; ++ni) {
      const int col = c0 + ni * 16 + ec;
      const int row = r0 + mi * 16 + er;
      float e[4];
#pragma unroll
      for (int r = 0; r < 4; ++r) {
        e[r] = exp2f(acc[mi][ni][r] * 1.44269504088896340736f);
        rs[r] += e[r];
      }
      const uint32_t p0 = f2bf2(e[0], e[1]);
      const uint32_t p1 = f2bf2(e[2], e[3]);
      C[(size_t)(row + 0) * 2048 + col] = (u16)p0;
      C[(size_t)(row + 1) * 2048 + col] = (u16)(p0 >> 16);
      C[(size_t)(row + 2) * 2048 + col] = (u16)p1;
      C[(size_t)(row + 3) * 2048 + col] = (u16)(p1 >> 16);
    }
#pragma unroll
    for (int o = 1; o < 16; o <<= 1)
#pragma unroll
      for (int r = 0; r < 4; ++r) rs[r] += __shfl_xor(rs[r], o);
    if ((lane & 15) == 0) {
#pragma unroll
      for (int r = 0; r < 4; ++r)
        atomicAdd(&lz[r0 + mi * 16 + er + r], rs[r]);
    }
  }
}

// ---------------- out += (P~ Vt^T)*inv, TM=128, SPLIT-K (K=2048 -> 2x1024) ----------------
// grid (256,1,4) = 1024 blocks = 4 blk/CU (pv previously ran 512 blocks = 2/CU).
// Per XCD: 4mt x 4nt x 2kh.  Both K-halves scale by 1/lsum and atomicAdd into zeroed out.
__global__ __launch_bounds__(256, 4)
void pv_k(const u16* __restrict__ P, const u16* __restrict__ Vt,
          float* __restrict__ out, const float* __restrict__ lsum) {
  __shared__ u16 ldsA[128 * 64];
  __shared__ u16 ldsB[128 * 64];
  const int lane = threadIdx.x & 63;
  const int wave = threadIdx.x >> 6;
  const int z = blockIdx.z;
  const int c = blockIdx.x & 7, j = blockIdx.x >> 3;   // j 0..31
  const int mt = 4 * (c >> 1) + (j & 3);               // 0..15
  const int nt = 4 * (c & 1) + ((j >> 2) & 3);         // 0..7
  const int kh = j >> 4;                               // 0..1 (K half)
  const u16* Ab = P + (size_t)z * 4194304 + (size_t)mt * 128 * 2048 + kh * 1024;
  const u16* Bb = Vt + (size_t)z * 2097152 + (size_t)nt * 128 * 2048 + kh * 1024;

  floatx4 acc[4][4] = {};
  kloop<128, 2048, 1024>(Ab, Bb, ldsA, ldsB, lane, wave, acc);

  const int wm = (wave >> 1) * 64;
  const int wn = (wave & 1) * 64;
  const int er = (lane >> 4) * 4;
  const int ec = lane & 15;
  const int r0 = mt * 128 + wm;
  const int c0 = nt * 128 + wn;
  float* C = out + (size_t)z * 2097152;
  const float* lz = lsum + z * 2048;
#pragma unroll
  for (int mi = 0; mi < 4; ++mi) {
    float inv[4];
#pragma unroll
    for (int r = 0; r < 4; ++r) inv[r] = 1.0f / lz[r0 + mi * 16 + er + r];
#pragma unroll
    for (int ni = 0; ni < 4; ++ni) {
      const int col = c0 + ni * 16 + ec;
#pragma unroll
      for (int r = 0; r < 4; ++r) {
        const int row = r0 + mi * 16 + er + r;
        atomicAdd(&C[(size_t)row * 1024 + col], acc[mi][ni][r] * inv[r]);
      }
    }
  }
}

extern "C" void kernel_launch(void* const* d_in, const int* in_sizes, int n_in,
                              void* d_out, int out_size, void* d_ws, size_t ws_size,
                              hipStream_t stream) {
  const float* x  = (const float*)d_in[0];
  const float* Wq = (const float*)d_in[1];
  const float* bq = (const float*)d_in[2];
  const float* Wk = (const float*)d_in[3];
  const float* bk = (const float*)d_in[4];
  const float* Wv = (const float*)d_in[5];
  const float* bv = (const float*)d_in[6];
  float* out = (float*)d_out;

  char* ws = (char*)d_ws;
  const size_t MB = 1ull << 20;
  u16* Q    = (u16*)(ws + 0 * MB);    // [2][8192][1024] bf16: Q,K contiguous
  u16* Vt   = (u16*)(ws + 48 * MB);   // [4][1024][2048]
  u16* Xb   = (u16*)(ws + 64 * MB);   // [8192][1024]
  u16* Wt   = (u16*)(ws + 80 * MB);   // [3][1024][1024]
  float* bias = (float*)(ws + 86 * MB);  // [3][1024]
  float* lsum = (float*)(ws + 87 * MB);  // [4][2048] softmax denominators
  u16* P    = (u16*)(ws + 88 * MB);   // [4][2048][2048] exp(scores), ends 120MB
  (void)ws_size; (void)in_sizes; (void)n_in; (void)out_size;

  // 1) fused prep: x->bf16, W->Wt, bias gather, lsum zero, out zero
  prep<<<13312, 256, 0, stream>>>(x, Wq, Wk, Wv, bq, bk, bv, Xb, Wt, bias, lsum, out);
  // 2) fused QKV + Vt projection (Q pre-scaled by 1/32), TM=128, swizzled LDS
  qkv_fused<<<dim3(64, 8, 3), 256, 0, stream>>>(Xb, Wt, Q, Vt, bias);
  // 3) P~ = exp(Q K^T), row sums -> lsum.  TM=128, 1024 blocks = 4 blk/CU.
  score_k<<<dim3(256, 1, 4), 256, 0, stream>>>(Q, P, lsum);
  // 4) out += (P~ V)*inv, split-K: 1024 blocks = 4 blk/CU (was 512 = 2/CU).
  pv_k<<<dim3(256, 1, 4), 256, 0, stream>>>(P, Vt, out, lsum);
}

// Round 9
// 230.456 us; speedup vs baseline: 2.2461x; 1.1887x over previous
//
#include <hip/hip_runtime.h>
#include <hip/hip_bf16.h>
#include <stdint.h>

typedef unsigned short u16;
typedef __attribute__((ext_vector_type(8))) short short8;   // 8 x bf16 (4 VGPRs) MFMA A/B frag
typedef __attribute__((ext_vector_type(4))) float floatx4;  // MFMA C/D frag

#define BATCH 4
#define SEQ   2048
#define DIM   1024

__device__ inline u16 f2bf(float f) {
  union { float f; uint32_t u; } v; v.f = f;
  uint32_t r = v.u + 0x7fffu + ((v.u >> 16) & 1u);  // RNE
  return (u16)(r >> 16);
}

// packed fp32x2 -> bf16x2 (v_cvt_pk_bf16_f32 on gfx950), RNE — bit-identical to f2bf
__device__ inline uint32_t f2bf2(float lo, float hi) {
  __hip_bfloat162 h = __float22bfloat162_rn(float2{lo, hi});
  union { __hip_bfloat162 h; uint32_t u; } v; v.h = h;
  return v.u;
}

// async global->LDS, 16B per lane; LDS dest is wave-uniform base (+lane*16 by HW)
__device__ inline void gload_lds16(const u16* g, u16* l) {
  __builtin_amdgcn_global_load_lds((const __attribute__((address_space(1))) uint32_t*)g,
                                   (__attribute__((address_space(3))) uint32_t*)l,
                                   16, 0, 0);
}

// ---------------- fused prep: x->bf16, W->Wt bf16, bias gather, lsum zero ----------------
// blocks [0,8192): cvt x.  blocks [8192,11264): transpose W (32x32 tile each).
__global__ __launch_bounds__(256) void prep(const float* __restrict__ x,
                                            const float* __restrict__ Wq,
                                            const float* __restrict__ Wk,
                                            const float* __restrict__ Wv,
                                            const float* __restrict__ bq,
                                            const float* __restrict__ bk,
                                            const float* __restrict__ bv,
                                            u16* __restrict__ Xb,
                                            u16* __restrict__ Wt,
                                            float* __restrict__ bias,
                                            float* __restrict__ lsum) {
  __shared__ u16 tile[32][33];
  const int bx = blockIdx.x;
  if (bx < 8192) {
    size_t i = ((size_t)bx * 256 + threadIdx.x) * 4;
    float4 v = *(const float4*)(x + i);
    uint2 o;
    o.x = f2bf2(v.x, v.y);
    o.y = f2bf2(v.z, v.w);
    *(uint2*)(Xb + i) = o;
    if (bx < 8) {  // zero 8192 floats of lsum
      float4 z = {0.f, 0.f, 0.f, 0.f};
      *(float4*)(lsum + (size_t)bx * 1024 + threadIdx.x * 4) = z;
    }
    return;
  }
  const int t = bx - 8192;
  const int tz = t >> 10;            // 0..2  (weight index)
  const int bxx = t & 31;            // 32 col-tiles
  const int byy = (t >> 5) & 31;     // 32 row-tiles
  const float* W = (tz == 0) ? Wq : (tz == 1) ? Wk : Wv;
  u16* o = Wt + (size_t)tz * (1u << 20);
  if (bxx == 0 && byy == 0) {  // pack biases contiguously
    const float* bsrc = (tz == 0) ? bq : (tz == 1) ? bk : bv;
    float4 b4 = *(const float4*)(bsrc + threadIdx.x * 4);
    *(float4*)(bias + tz * 1024 + threadIdx.x * 4) = b4;
  }
  int c0 = bxx * 32, r0 = byy * 32;
  int tx = threadIdx.x & 31, ty = threadIdx.x >> 5;  // ty 0..7
#pragma unroll
  for (int p = 0; p < 4; ++p)
    tile[p * 8 + ty][tx] = f2bf(W[(size_t)(r0 + p * 8 + ty) * DIM + c0 + tx]);
  __syncthreads();
#pragma unroll
  for (int p = 0; p < 4; ++p)
    o[(size_t)(c0 + p * 8 + ty) * DIM + r0 + tx] = tile[tx][p * 8 + ty];
}

// LDS swizzle (both-sides, rule #21): slot s of row r holds source k-chunk s^((r>>1)&3).
// Staging: gload_lds dest stays linear; SOURCE chunk = (lane&3)^((lane>>3)&3).
// Read: chunk slot = (lane>>4)^((fr>>1)&3), fr=lane&15.  Verified 0 conflicts (r1-r8).

// ---------------- shared K-loop body (m97-class: BK=64, 2-barrier, gload_lds w=16) ----------------
// LD = row stride (leading dim), KLEN = k extent of this block's slice.
template <int TM, int LD, int KLEN>
__device__ __forceinline__ void kloop(const u16* __restrict__ Ab, const u16* __restrict__ Bb,
                                      u16* __restrict__ ldsA, u16* __restrict__ ldsB,
                                      int lane, int wave, floatx4 (&acc)[TM / 32][4]) {
  constexpr int MI = TM / 32;
  constexpr int AS = TM / 64;
  const int sr = lane >> 2;
  const int sc = ((lane & 3) ^ ((lane >> 3) & 3)) * 8;   // pre-swizzled source chunk
  const u16* gA0 = Ab + (size_t)(wave * (TM / 4) + sr) * LD + sc;
  const u16* gB0 = Bb + (size_t)(wave * 32 + sr) * LD + sc;
  u16* lA0 = ldsA + wave * (TM / 4) * 32;
  u16* lB0 = ldsB + wave * 1024;
  constexpr int SLA = TM * 32;
  constexpr int SLB = 4096;

  const int wm = (wave >> 1) * (TM / 2);
  const int wn = (wave & 1) * 64;
  const int fr = lane & 15;
  const int fk = ((lane >> 4) ^ ((fr >> 1) & 3)) * 8;    // swizzled read chunk
  const u16* la = ldsA + (wm + fr) * 32 + fk;
  const u16* lb = ldsB + (wn + fr) * 32 + fk;

  for (int kt = 0; kt < KLEN; kt += 64) {
    __syncthreads();
#pragma unroll
    for (int i = 0; i < AS; ++i) {
      gload_lds16(gA0 + kt + (size_t)(16 * i) * LD, lA0 + i * 512);
      gload_lds16(gA0 + kt + 32 + (size_t)(16 * i) * LD, lA0 + SLA + i * 512);
    }
#pragma unroll
    for (int i = 0; i < 2; ++i) {
      gload_lds16(gB0 + kt + (size_t)(16 * i) * LD, lB0 + i * 512);
      gload_lds16(gB0 + kt + 32 + (size_t)(16 * i) * LD, lB0 + SLB + i * 512);
    }
    __syncthreads();
#pragma unroll
    for (int ks = 0; ks < 2; ++ks) {
      short8 a[MI], b[4];
#pragma unroll
      for (int i = 0; i < MI; ++i)
        a[i] = *(const short8*)(la + ks * SLA + i * 512);
#pragma unroll
      for (int i = 0; i < 4; ++i)
        b[i] = *(const short8*)(lb + ks * SLB + i * 512);
#pragma unroll
      for (int mi = 0; mi < MI; ++mi)
#pragma unroll
        for (int ni = 0; ni < 4; ++ni)
          acc[mi][ni] = __builtin_amdgcn_mfma_f32_16x16x32_bf16(a[mi], b[ni], acc[mi][ni], 0, 0, 0);
    }
  }
}

// ---------------- fused QKV+Vt projection, TM=128, BK=64 ----------------
// grid (64,8,3).  z in {0,1}: Q/K = Xb x Wt[z] + b, bf16 -> Q (+ 1/32 for z=0).
// z==2: Vt[b][h][s] = (Wv^T x^T + bv), column-demuxed store.
__global__ __launch_bounds__(256, 4)
void qkv_fused(const u16* __restrict__ Xb, const u16* __restrict__ Wt,
               u16* __restrict__ Q, u16* __restrict__ Vt,
               const float* __restrict__ bias) {
  __shared__ u16 ldsA[128 * 64];
  __shared__ u16 ldsB[128 * 64];
  const int lane = threadIdx.x & 63;
  const int wave = threadIdx.x >> 6;
  const int z = blockIdx.z;

  int mt, nt, N;
  const u16 *Ab, *Bb;
  if (z < 2) {             // Q/K projection: A = Xb rows, B = Wt[z] rows
    mt = blockIdx.x; nt = blockIdx.y; N = 1024;
    Ab = Xb + (size_t)mt * 128 * 1024;
    Bb = Wt + (size_t)z * (1u << 20) + (size_t)nt * 128 * 1024;
  } else {                 // Vt projection: A = Wv^T rows (h), B = Xb rows (s)
    nt = blockIdx.x; mt = blockIdx.y; N = 8192;
    Ab = Wt + (size_t)2 * (1u << 20) + (size_t)mt * 128 * 1024;
    Bb = Xb + (size_t)nt * 128 * 1024;
  }

  floatx4 acc[4][4] = {};
  kloop<128, 1024, 1024>(Ab, Bb, ldsA, ldsB, lane, wave, acc);

  const int wm = (wave >> 1) * 64;
  const int wn = (wave & 1) * 64;
  const int er = (lane >> 4) * 4;
  const int ec = lane & 15;
  const int r0 = mt * 128 + wm;
  const int c0 = nt * 128 + wn;

  if (z < 2) {
    u16* C = Q + (size_t)z * (8u << 20);
    const float* bz = bias + z * 1024;
    const float zs = (z == 0) ? 0.03125f : 1.0f;  // fold 1/sqrt(1024) into Q
#pragma unroll
    for (int mi = 0; mi < 4; ++mi)
#pragma unroll
      for (int ni = 0; ni < 4; ++ni) {
        const int col = c0 + ni * 16 + ec;
        const float bb = bz[col];
        const int row = r0 + mi * 16 + er;
        const uint32_t p0 = f2bf2((acc[mi][ni][0] + bb) * zs, (acc[mi][ni][1] + bb) * zs);
        const uint32_t p1 = f2bf2((acc[mi][ni][2] + bb) * zs, (acc[mi][ni][3] + bb) * zs);
        C[(size_t)(row + 0) * N + col] = (u16)p0;
        C[(size_t)(row + 1) * N + col] = (u16)(p0 >> 16);
        C[(size_t)(row + 2) * N + col] = (u16)p1;
        C[(size_t)(row + 3) * N + col] = (u16)(p1 >> 16);
      }
  } else {
    const float* bz = bias + 2 * 1024;  // bv, indexed by row (=h)
#pragma unroll
    for (int mi = 0; mi < 4; ++mi) {
      float bb[4];
#pragma unroll
      for (int r = 0; r < 4; ++r) bb[r] = bz[r0 + mi * 16 + er + r];
#pragma unroll
      for (int ni = 0; ni < 4; ++ni) {
        const int col = c0 + ni * 16 + ec;
        const size_t base = (size_t)(col >> 11) * (1u << 21) + (col & 2047);
        const int row = r0 + mi * 16 + er;
        const uint32_t p0 = f2bf2(acc[mi][ni][0] + bb[0], acc[mi][ni][1] + bb[1]);
        const uint32_t p1 = f2bf2(acc[mi][ni][2] + bb[2], acc[mi][ni][3] + bb[3]);
        Vt[base + (size_t)(row + 0) * 2048] = (u16)p0;
        Vt[base + (size_t)(row + 1) * 2048] = (u16)(p0 >> 16);
        Vt[base + (size_t)(row + 2) * 2048] = (u16)p1;
        Vt[base + (size_t)(row + 3) * 2048] = (u16)(p1 >> 16);
      }
    }
  }
}

// ---------------- P~ = exp(Q K^T), TM=128, grid (256,1,4) = 1024 blocks = 4 blk/CU ----------------
// (r6-measured best score config: left the top-5 at <60 us vs 70.6 for TM=256@2/CU)
__global__ __launch_bounds__(256, 4)
void score_k(const u16* __restrict__ Q, u16* __restrict__ P, float* __restrict__ lsum) {
  __shared__ u16 ldsA[128 * 64];
  __shared__ u16 ldsB[128 * 64];
  const int lane = threadIdx.x & 63;
  const int wave = threadIdx.x >> 6;
  const int z = blockIdx.z;
  const int c = blockIdx.x & 7, j = blockIdx.x >> 3;
  const int mt = 4 * (c >> 1) + (j & 3);       // 0..15
  const int nt = 8 * (c & 1) + (j >> 2);       // 0..15
  const u16* Ab = Q + (size_t)z * 2097152 + (size_t)mt * 128 * 1024;
  const u16* Bb = Q + 8388608 + (size_t)z * 2097152 + (size_t)nt * 128 * 1024;

  floatx4 acc[4][4] = {};
  kloop<128, 1024, 1024>(Ab, Bb, ldsA, ldsB, lane, wave, acc);

  const int wm = (wave >> 1) * 64;
  const int wn = (wave & 1) * 64;
  const int er = (lane >> 4) * 4;
  const int ec = lane & 15;
  const int r0 = mt * 128 + wm;
  const int c0 = nt * 128 + wn;
  u16* C = P + (size_t)z * 4194304;
  float* lz = lsum + z * 2048;
#pragma unroll
  for (int mi = 0; mi < 4; ++mi) {
    float rs[4] = {0.f, 0.f, 0.f, 0.f};
#pragma unroll
    for (int ni = 0; ni < 4; ++ni) {
      const int col = c0 + ni * 16 + ec;
      const int row = r0 + mi * 16 + er;
      float e[4];
#pragma unroll
      for (int r = 0; r < 4; ++r) {
        e[r] = exp2f(acc[mi][ni][r] * 1.44269504088896340736f);
        rs[r] += e[r];
      }
      const uint32_t p0 = f2bf2(e[0], e[1]);
      const uint32_t p1 = f2bf2(e[2], e[3]);
      C[(size_t)(row + 0) * 2048 + col] = (u16)p0;
      C[(size_t)(row + 1) * 2048 + col] = (u16)(p0 >> 16);
      C[(size_t)(row + 2) * 2048 + col] = (u16)p1;
      C[(size_t)(row + 3) * 2048 + col] = (u16)(p1 >> 16);
    }
#pragma unroll
    for (int o = 1; o < 16; o <<= 1)
#pragma unroll
      for (int r = 0; r < 4; ++r) rs[r] += __shfl_xor(rs[r], o);
    if ((lane & 15) == 0) {
#pragma unroll
      for (int r = 0; r < 4; ++r)
        atomicAdd(&lz[r0 + mi * 16 + er + r], rs[r]);
    }
  }
}

// ---------------- out = (P~ Vt^T)/lsum, TM=128, K=2048, grid (128,1,4) = 512 blocks ----------------
// (r5/r0-measured best pv config: plain stores, no split-K, 16mt x 8nt, 4m x 4n per XCD)
__global__ __launch_bounds__(256, 4)
void pv_k(const u16* __restrict__ P, const u16* __restrict__ Vt,
          float* __restrict__ out, const float* __restrict__ lsum) {
  __shared__ u16 ldsA[128 * 64];
  __shared__ u16 ldsB[128 * 64];
  const int lane = threadIdx.x & 63;
  const int wave = threadIdx.x >> 6;
  const int z = blockIdx.z;
  const int c = blockIdx.x & 7, j = blockIdx.x >> 3;   // j 0..15
  const int mt = 4 * (c >> 1) + (j & 3);               // 0..15
  const int nt = 4 * (c & 1) + (j >> 2);               // 0..7
  const u16* Ab = P + (size_t)z * 4194304 + (size_t)mt * 128 * 2048;
  const u16* Bb = Vt + (size_t)z * 2097152 + (size_t)nt * 128 * 2048;

  floatx4 acc[4][4] = {};
  kloop<128, 2048, 2048>(Ab, Bb, ldsA, ldsB, lane, wave, acc);

  const int wm = (wave >> 1) * 64;
  const int wn = (wave & 1) * 64;
  const int er = (lane >> 4) * 4;
  const int ec = lane & 15;
  const int r0 = mt * 128 + wm;
  const int c0 = nt * 128 + wn;
  float* C = out + (size_t)z * 2097152;
  const float* lz = lsum + z * 2048;
#pragma unroll
  for (int mi = 0; mi < 4; ++mi) {
    float inv[4];
#pragma unroll
    for (int r = 0; r < 4; ++r) inv[r] = 1.0f / lz[r0 + mi * 16 + er + r];
#pragma unroll
    for (int ni = 0; ni < 4; ++ni) {
      const int col = c0 + ni * 16 + ec;
#pragma unroll
      for (int r = 0; r < 4; ++r) {
        const int row = r0 + mi * 16 + er + r;
        C[(size_t)row * 1024 + col] = acc[mi][ni][r] * inv[r];
      }
    }
  }
}

extern "C" void kernel_launch(void* const* d_in, const int* in_sizes, int n_in,
                              void* d_out, int out_size, void* d_ws, size_t ws_size,
                              hipStream_t stream) {
  const float* x  = (const float*)d_in[0];
  const float* Wq = (const float*)d_in[1];
  const float* bq = (const float*)d_in[2];
  const float* Wk = (const float*)d_in[3];
  const float* bk = (const float*)d_in[4];
  const float* Wv = (const float*)d_in[5];
  const float* bv = (const float*)d_in[6];
  float* out = (float*)d_out;

  char* ws = (char*)d_ws;
  const size_t MB = 1ull << 20;
  u16* Q    = (u16*)(ws + 0 * MB);    // [2][8192][1024] bf16: Q,K contiguous
  u16* Vt   = (u16*)(ws + 48 * MB);   // [4][1024][2048]
  u16* Xb   = (u16*)(ws + 64 * MB);   // [8192][1024]
  u16* Wt   = (u16*)(ws + 80 * MB);   // [3][1024][1024]
  float* bias = (float*)(ws + 86 * MB);  // [3][1024]
  float* lsum = (float*)(ws + 87 * MB);  // [4][2048] softmax denominators
  u16* P    = (u16*)(ws + 88 * MB);   // [4][2048][2048] exp(scores), ends 120MB
  (void)ws_size; (void)in_sizes; (void)n_in; (void)out_size;

  // 1) fused prep: x->bf16, W->Wt, bias gather, lsum zero
  prep<<<11264, 256, 0, stream>>>(x, Wq, Wk, Wv, bq, bk, bv, Xb, Wt, bias, lsum);
  // 2) fused QKV + Vt projection (Q pre-scaled by 1/32), TM=128, swizzled LDS
  qkv_fused<<<dim3(64, 8, 3), 256, 0, stream>>>(Xb, Wt, Q, Vt, bias);
  // 3) P~ = exp(Q K^T), row sums -> lsum.  TM=128, 1024 blocks = 4 blk/CU (r6-best).
  score_k<<<dim3(256, 1, 4), 256, 0, stream>>>(Q, P, lsum);
  // 4) out = (P~ V)/lsum.  TM=128, 512 blocks, plain stores (r5-best).
  pv_k<<<dim3(128, 1, 4), 256, 0, stream>>>(P, Vt, out, lsum);
}

// Round 10
// 225.125 us; speedup vs baseline: 2.2993x; 1.0237x over previous
//
#include <hip/hip_runtime.h>
#include <hip/hip_bf16.h>
#include <stdint.h>

typedef unsigned short u16;
typedef __attribute__((ext_vector_type(8))) short short8;   // 8 x bf16 (4 VGPRs) MFMA A/B frag
typedef __attribute__((ext_vector_type(4))) float floatx4;  // MFMA C/D frag

#define BATCH 4
#define SEQ   2048
#define DIM   1024

__device__ inline u16 f2bf(float f) {
  union { float f; uint32_t u; } v; v.f = f;
  uint32_t r = v.u + 0x7fffu + ((v.u >> 16) & 1u);  // RNE
  return (u16)(r >> 16);
}

// packed fp32x2 -> bf16x2 (v_cvt_pk_bf16_f32 on gfx950), RNE — bit-identical to f2bf
__device__ inline uint32_t f2bf2(float lo, float hi) {
  __hip_bfloat162 h = __float22bfloat162_rn(float2{lo, hi});
  union { __hip_bfloat162 h; uint32_t u; } v; v.h = h;
  return v.u;
}

// async global->LDS, 16B per lane; LDS dest is wave-uniform base (+lane*16 by HW)
__device__ inline void gload_lds16(const u16* g, u16* l) {
  __builtin_amdgcn_global_load_lds((const __attribute__((address_space(1))) uint32_t*)g,
                                   (__attribute__((address_space(3))) uint32_t*)l,
                                   16, 0, 0);
}

// ---------------- fused prep: x->bf16, W->Wt bf16, bias gather, lsum zero ----------------
// blocks [0,8192): cvt x.  blocks [8192,11264): transpose W (32x32 tile each).
__global__ __launch_bounds__(256) void prep(const float* __restrict__ x,
                                            const float* __restrict__ Wq,
                                            const float* __restrict__ Wk,
                                            const float* __restrict__ Wv,
                                            const float* __restrict__ bq,
                                            const float* __restrict__ bk,
                                            const float* __restrict__ bv,
                                            u16* __restrict__ Xb,
                                            u16* __restrict__ Wt,
                                            float* __restrict__ bias,
                                            float* __restrict__ lsum) {
  __shared__ u16 tile[32][33];
  const int bx = blockIdx.x;
  if (bx < 8192) {
    size_t i = ((size_t)bx * 256 + threadIdx.x) * 4;
    float4 v = *(const float4*)(x + i);
    uint2 o;
    o.x = f2bf2(v.x, v.y);
    o.y = f2bf2(v.z, v.w);
    *(uint2*)(Xb + i) = o;
    if (bx < 8) {  // zero 8192 floats of lsum
      float4 z = {0.f, 0.f, 0.f, 0.f};
      *(float4*)(lsum + (size_t)bx * 1024 + threadIdx.x * 4) = z;
    }
    return;
  }
  const int t = bx - 8192;
  const int tz = t >> 10;            // 0..2  (weight index)
  const int bxx = t & 31;            // 32 col-tiles
  const int byy = (t >> 5) & 31;     // 32 row-tiles
  const float* W = (tz == 0) ? Wq : (tz == 1) ? Wk : Wv;
  u16* o = Wt + (size_t)tz * (1u << 20);
  if (bxx == 0 && byy == 0) {  // pack biases contiguously
    const float* bsrc = (tz == 0) ? bq : (tz == 1) ? bk : bv;
    float4 b4 = *(const float4*)(bsrc + threadIdx.x * 4);
    *(float4*)(bias + tz * 1024 + threadIdx.x * 4) = b4;
  }
  int c0 = bxx * 32, r0 = byy * 32;
  int tx = threadIdx.x & 31, ty = threadIdx.x >> 5;  // ty 0..7
#pragma unroll
  for (int p = 0; p < 4; ++p)
    tile[p * 8 + ty][tx] = f2bf(W[(size_t)(r0 + p * 8 + ty) * DIM + c0 + tx]);
  __syncthreads();
#pragma unroll
  for (int p = 0; p < 4; ++p)
    o[(size_t)(c0 + p * 8 + ty) * DIM + r0 + tx] = tile[tx][p * 8 + ty];
}

// LDS swizzle (both-sides, rule #21), BK=64 kernels: slot s of row r holds source
// k-chunk s^((r>>1)&3); staging source chunk = (lane&3)^((lane>>3)&3), read chunk
// slot = (lane>>4)^((fr>>1)&3).  Verified 0 conflicts (r1-r9).

// ---------------- shared K-loop body (m97-class: BK=64, 2-barrier, gload_lds w=16) ----------------
// LD = row stride (leading dim), KLEN = k extent of this block's slice.
template <int TM, int LD, int KLEN>
__device__ __forceinline__ void kloop(const u16* __restrict__ Ab, const u16* __restrict__ Bb,
                                      u16* __restrict__ ldsA, u16* __restrict__ ldsB,
                                      int lane, int wave, floatx4 (&acc)[TM / 32][4]) {
  constexpr int MI = TM / 32;
  constexpr int AS = TM / 64;
  const int sr = lane >> 2;
  const int sc = ((lane & 3) ^ ((lane >> 3) & 3)) * 8;   // pre-swizzled source chunk
  const u16* gA0 = Ab + (size_t)(wave * (TM / 4) + sr) * LD + sc;
  const u16* gB0 = Bb + (size_t)(wave * 32 + sr) * LD + sc;
  u16* lA0 = ldsA + wave * (TM / 4) * 32;
  u16* lB0 = ldsB + wave * 1024;
  constexpr int SLA = TM * 32;
  constexpr int SLB = 4096;

  const int wm = (wave >> 1) * (TM / 2);
  const int wn = (wave & 1) * 64;
  const int fr = lane & 15;
  const int fk = ((lane >> 4) ^ ((fr >> 1) & 3)) * 8;    // swizzled read chunk
  const u16* la = ldsA + (wm + fr) * 32 + fk;
  const u16* lb = ldsB + (wn + fr) * 32 + fk;

  for (int kt = 0; kt < KLEN; kt += 64) {
    __syncthreads();
#pragma unroll
    for (int i = 0; i < AS; ++i) {
      gload_lds16(gA0 + kt + (size_t)(16 * i) * LD, lA0 + i * 512);
      gload_lds16(gA0 + kt + 32 + (size_t)(16 * i) * LD, lA0 + SLA + i * 512);
    }
#pragma unroll
    for (int i = 0; i < 2; ++i) {
      gload_lds16(gB0 + kt + (size_t)(16 * i) * LD, lB0 + i * 512);
      gload_lds16(gB0 + kt + 32 + (size_t)(16 * i) * LD, lB0 + SLB + i * 512);
    }
    __syncthreads();
#pragma unroll
    for (int ks = 0; ks < 2; ++ks) {
      short8 a[MI], b[4];
#pragma unroll
      for (int i = 0; i < MI; ++i)
        a[i] = *(const short8*)(la + ks * SLA + i * 512);
#pragma unroll
      for (int i = 0; i < 4; ++i)
        b[i] = *(const short8*)(lb + ks * SLB + i * 512);
#pragma unroll
      for (int mi = 0; mi < MI; ++mi)
#pragma unroll
        for (int ni = 0; ni < 4; ++ni)
          acc[mi][ni] = __builtin_amdgcn_mfma_f32_16x16x32_bf16(a[mi], b[ni], acc[mi][ni], 0, 0, 0);
    }
  }
}

// ---------------- BK=128 K-loop (pv only: res-2 regime, halves barrier count) ----------------
// LDS tile [TM|128 rows][128 cols], 256B rows.  Swizzle: LDS 16B-slot s of row r holds
// source chunk s^(r&7).  Staging instr i covers 4 rows (lane>>4), dest slot lane&15,
// source chunk = (lane&15) ^ ((i*4 + (lane>>4))&7) = sce ^ ((i&1)*4 with sce=(ci^q)*8.
// Read: G-chunk ks*4+q lives at slot (ks*4+q)^(fr&7).  Round-trip: LDS[r][s]=G[r][s^(r&7)].
template <int TM, int LD, int KLEN>
__device__ __forceinline__ void kloop128(const u16* __restrict__ Ab, const u16* __restrict__ Bb,
                                         u16* __restrict__ ldsA, u16* __restrict__ ldsB,
                                         int lane, int wave, floatx4 (&acc)[TM / 32][4]) {
  constexpr int MI = TM / 32;
  constexpr int AI = TM / 16;          // A gload instrs per wave (4 rows each)
  const int q  = lane >> 4;            // 0..3: staging row-in-group / read k-chunk group
  const int ci = lane & 15;            // staging dest 16B-slot within row
  const int sce = (ci ^ q) * 8;        // source chunk offset (u16) for even i; odd i: ^32
  const u16* gA0 = Ab + (size_t)(wave * (TM / 4) + q) * LD;
  const u16* gB0 = Bb + (size_t)(wave * 32 + q) * LD;
  u16* lA0 = ldsA + wave * (TM / 4) * 128;
  u16* lB0 = ldsB + wave * 32 * 128;

  const int wm = (wave >> 1) * (TM / 2);
  const int wn = (wave & 1) * 64;
  const int fr = lane & 15;
  const int key = fr & 7;
  const u16* la = ldsA + (wm + fr) * 128;
  const u16* lb = ldsB + (wn + fr) * 128;

  for (int kt = 0; kt < KLEN; kt += 128) {
    __syncthreads();
#pragma unroll
    for (int i = 0; i < AI; ++i)
      gload_lds16(gA0 + (size_t)(i * 4) * LD + kt + ((i & 1) ? (sce ^ 32) : sce),
                  lA0 + i * 512);
#pragma unroll
    for (int i = 0; i < 8; ++i)
      gload_lds16(gB0 + (size_t)(i * 4) * LD + kt + ((i & 1) ? (sce ^ 32) : sce),
                  lB0 + i * 512);
    __syncthreads();
#pragma unroll
    for (int ks = 0; ks < 4; ++ks) {
      const int co = (((ks * 4 + q) ^ key) * 8);   // swizzled read slot (u16 offset)
      short8 a[MI], b[4];
#pragma unroll
      for (int i = 0; i < MI; ++i)
        a[i] = *(const short8*)(la + i * 2048 + co);
#pragma unroll
      for (int i = 0; i < 4; ++i)
        b[i] = *(const short8*)(lb + i * 2048 + co);
#pragma unroll
      for (int mi = 0; mi < MI; ++mi)
#pragma unroll
        for (int ni = 0; ni < 4; ++ni)
          acc[mi][ni] = __builtin_amdgcn_mfma_f32_16x16x32_bf16(a[mi], b[ni], acc[mi][ni], 0, 0, 0);
    }
  }
}

// ---------------- fused QKV+Vt projection, TM=128, BK=64 ----------------
// grid (64,8,3).  z in {0,1}: Q/K = Xb x Wt[z] + b, bf16 -> Q (+ 1/32 for z=0).
// z==2: Vt[b][h][s] = (Wv^T x^T + bv), column-demuxed store.
__global__ __launch_bounds__(256, 4)
void qkv_fused(const u16* __restrict__ Xb, const u16* __restrict__ Wt,
               u16* __restrict__ Q, u16* __restrict__ Vt,
               const float* __restrict__ bias) {
  __shared__ u16 ldsA[128 * 64];
  __shared__ u16 ldsB[128 * 64];
  const int lane = threadIdx.x & 63;
  const int wave = threadIdx.x >> 6;
  const int z = blockIdx.z;

  int mt, nt, N;
  const u16 *Ab, *Bb;
  if (z < 2) {             // Q/K projection: A = Xb rows, B = Wt[z] rows
    mt = blockIdx.x; nt = blockIdx.y; N = 1024;
    Ab = Xb + (size_t)mt * 128 * 1024;
    Bb = Wt + (size_t)z * (1u << 20) + (size_t)nt * 128 * 1024;
  } else {                 // Vt projection: A = Wv^T rows (h), B = Xb rows (s)
    nt = blockIdx.x; mt = blockIdx.y; N = 8192;
    Ab = Wt + (size_t)2 * (1u << 20) + (size_t)mt * 128 * 1024;
    Bb = Xb + (size_t)nt * 128 * 1024;
  }

  floatx4 acc[4][4] = {};
  kloop<128, 1024, 1024>(Ab, Bb, ldsA, ldsB, lane, wave, acc);

  const int wm = (wave >> 1) * 64;
  const int wn = (wave & 1) * 64;
  const int er = (lane >> 4) * 4;
  const int ec = lane & 15;
  const int r0 = mt * 128 + wm;
  const int c0 = nt * 128 + wn;

  if (z < 2) {
    u16* C = Q + (size_t)z * (8u << 20);
    const float* bz = bias + z * 1024;
    const float zs = (z == 0) ? 0.03125f : 1.0f;  // fold 1/sqrt(1024) into Q
#pragma unroll
    for (int mi = 0; mi < 4; ++mi)
#pragma unroll
      for (int ni = 0; ni < 4; ++ni) {
        const int col = c0 + ni * 16 + ec;
        const float bb = bz[col];
        const int row = r0 + mi * 16 + er;
        const uint32_t p0 = f2bf2((acc[mi][ni][0] + bb) * zs, (acc[mi][ni][1] + bb) * zs);
        const uint32_t p1 = f2bf2((acc[mi][ni][2] + bb) * zs, (acc[mi][ni][3] + bb) * zs);
        C[(size_t)(row + 0) * N + col] = (u16)p0;
        C[(size_t)(row + 1) * N + col] = (u16)(p0 >> 16);
        C[(size_t)(row + 2) * N + col] = (u16)p1;
        C[(size_t)(row + 3) * N + col] = (u16)(p1 >> 16);
      }
  } else {
    const float* bz = bias + 2 * 1024;  // bv, indexed by row (=h)
#pragma unroll
    for (int mi = 0; mi < 4; ++mi) {
      float bb[4];
#pragma unroll
      for (int r = 0; r < 4; ++r) bb[r] = bz[r0 + mi * 16 + er + r];
#pragma unroll
      for (int ni = 0; ni < 4; ++ni) {
        const int col = c0 + ni * 16 + ec;
        const size_t base = (size_t)(col >> 11) * (1u << 21) + (col & 2047);
        const int row = r0 + mi * 16 + er;
        const uint32_t p0 = f2bf2(acc[mi][ni][0] + bb[0], acc[mi][ni][1] + bb[1]);
        const uint32_t p1 = f2bf2(acc[mi][ni][2] + bb[2], acc[mi][ni][3] + bb[3]);
        Vt[base + (size_t)(row + 0) * 2048] = (u16)p0;
        Vt[base + (size_t)(row + 1) * 2048] = (u16)(p0 >> 16);
        Vt[base + (size_t)(row + 2) * 2048] = (u16)p1;
        Vt[base + (size_t)(row + 3) * 2048] = (u16)(p1 >> 16);
      }
    }
  }
}

// ---------------- P~ = exp(Q K^T), TM=128, grid (256,1,4) = 1024 blocks = 4 blk/CU ----------------
__global__ __launch_bounds__(256, 4)
void score_k(const u16* __restrict__ Q, u16* __restrict__ P, float* __restrict__ lsum) {
  __shared__ u16 ldsA[128 * 64];
  __shared__ u16 ldsB[128 * 64];
  const int lane = threadIdx.x & 63;
  const int wave = threadIdx.x >> 6;
  const int z = blockIdx.z;
  const int c = blockIdx.x & 7, j = blockIdx.x >> 3;
  const int mt = 4 * (c >> 1) + (j & 3);       // 0..15
  const int nt = 8 * (c & 1) + (j >> 2);       // 0..15
  const u16* Ab = Q + (size_t)z * 2097152 + (size_t)mt * 128 * 1024;
  const u16* Bb = Q + 8388608 + (size_t)z * 2097152 + (size_t)nt * 128 * 1024;

  floatx4 acc[4][4] = {};
  kloop<128, 1024, 1024>(Ab, Bb, ldsA, ldsB, lane, wave, acc);

  const int wm = (wave >> 1) * 64;
  const int wn = (wave & 1) * 64;
  const int er = (lane >> 4) * 4;
  const int ec = lane & 15;
  const int r0 = mt * 128 + wm;
  const int c0 = nt * 128 + wn;
  u16* C = P + (size_t)z * 4194304;
  float* lz = lsum + z * 2048;
#pragma unroll
  for (int mi = 0; mi < 4; ++mi) {
    float rs[4] = {0.f, 0.f, 0.f, 0.f};
#pragma unroll
    for (int ni = 0; ni < 4; ++ni) {
      const int col = c0 + ni * 16 + ec;
      const int row = r0 + mi * 16 + er;
      float e[4];
#pragma unroll
      for (int r = 0; r < 4; ++r) {
        e[r] = exp2f(acc[mi][ni][r] * 1.44269504088896340736f);
        rs[r] += e[r];
      }
      const uint32_t p0 = f2bf2(e[0], e[1]);
      const uint32_t p1 = f2bf2(e[2], e[3]);
      C[(size_t)(row + 0) * 2048 + col] = (u16)p0;
      C[(size_t)(row + 1) * 2048 + col] = (u16)(p0 >> 16);
      C[(size_t)(row + 2) * 2048 + col] = (u16)p1;
      C[(size_t)(row + 3) * 2048 + col] = (u16)(p1 >> 16);
    }
#pragma unroll
    for (int o = 1; o < 16; o <<= 1)
#pragma unroll
      for (int r = 0; r < 4; ++r) rs[r] += __shfl_xor(rs[r], o);
    if ((lane & 15) == 0) {
#pragma unroll
      for (int r = 0; r < 4; ++r)
        atomicAdd(&lz[r0 + mi * 16 + er + r], rs[r]);
    }
  }
}

// ---------------- out = (P~ Vt^T)/lsum, TM=128, K=2048, BK=128, grid (128,1,4) ----------------
// 512 blocks = 2 blk/CU (res fixed by tiling).  BK=128 halves barrier count at unchanged
// occupancy (LDS 64KB x 2 = 128KB <= 160).  Plain stores (split-K and TM/TN=64 both
// measured regressions).
__global__ __launch_bounds__(256, 2)
void pv_k(const u16* __restrict__ P, const u16* __restrict__ Vt,
          float* __restrict__ out, const float* __restrict__ lsum) {
  __shared__ u16 ldsA[128 * 128];
  __shared__ u16 ldsB[128 * 128];
  const int lane = threadIdx.x & 63;
  const int wave = threadIdx.x >> 6;
  const int z = blockIdx.z;
  const int c = blockIdx.x & 7, j = blockIdx.x >> 3;   // j 0..15
  const int mt = 4 * (c >> 1) + (j & 3);               // 0..15
  const int nt = 4 * (c & 1) + (j >> 2);               // 0..7
  const u16* Ab = P + (size_t)z * 4194304 + (size_t)mt * 128 * 2048;
  const u16* Bb = Vt + (size_t)z * 2097152 + (size_t)nt * 128 * 2048;

  floatx4 acc[4][4] = {};
  kloop128<128, 2048, 2048>(Ab, Bb, ldsA, ldsB, lane, wave, acc);

  const int wm = (wave >> 1) * 64;
  const int wn = (wave & 1) * 64;
  const int er = (lane >> 4) * 4;
  const int ec = lane & 15;
  const int r0 = mt * 128 + wm;
  const int c0 = nt * 128 + wn;
  float* C = out + (size_t)z * 2097152;
  const float* lz = lsum + z * 2048;
#pragma unroll
  for (int mi = 0; mi < 4; ++mi) {
    float inv[4];
#pragma unroll
    for (int r = 0; r < 4; ++r) inv[r] = 1.0f / lz[r0 + mi * 16 + er + r];
#pragma unroll
    for (int ni = 0; ni < 4; ++ni) {
      const int col = c0 + ni * 16 + ec;
#pragma unroll
      for (int r = 0; r < 4; ++r) {
        const int row = r0 + mi * 16 + er + r;
        C[(size_t)row * 1024 + col] = acc[mi][ni][r] * inv[r];
      }
    }
  }
}

extern "C" void kernel_launch(void* const* d_in, const int* in_sizes, int n_in,
                              void* d_out, int out_size, void* d_ws, size_t ws_size,
                              hipStream_t stream) {
  const float* x  = (const float*)d_in[0];
  const float* Wq = (const float*)d_in[1];
  const float* bq = (const float*)d_in[2];
  const float* Wk = (const float*)d_in[3];
  const float* bk = (const float*)d_in[4];
  const float* Wv = (const float*)d_in[5];
  const float* bv = (const float*)d_in[6];
  float* out = (float*)d_out;

  char* ws = (char*)d_ws;
  const size_t MB = 1ull << 20;
  u16* Q    = (u16*)(ws + 0 * MB);    // [2][8192][1024] bf16: Q,K contiguous
  u16* Vt   = (u16*)(ws + 48 * MB);   // [4][1024][2048]
  u16* Xb   = (u16*)(ws + 64 * MB);   // [8192][1024]
  u16* Wt   = (u16*)(ws + 80 * MB);   // [3][1024][1024]
  float* bias = (float*)(ws + 86 * MB);  // [3][1024]
  float* lsum = (float*)(ws + 87 * MB);  // [4][2048] softmax denominators
  u16* P    = (u16*)(ws + 88 * MB);   // [4][2048][2048] exp(scores), ends 120MB
  (void)ws_size; (void)in_sizes; (void)n_in; (void)out_size;

  // 1) fused prep: x->bf16, W->Wt, bias gather, lsum zero
  prep<<<11264, 256, 0, stream>>>(x, Wq, Wk, Wv, bq, bk, bv, Xb, Wt, bias, lsum);
  // 2) fused QKV + Vt projection (Q pre-scaled by 1/32), TM=128, swizzled LDS
  qkv_fused<<<dim3(64, 8, 3), 256, 0, stream>>>(Xb, Wt, Q, Vt, bias);
  // 3) P~ = exp(Q K^T), row sums -> lsum.  TM=128, 1024 blocks = 4 blk/CU.
  score_k<<<dim3(256, 1, 4), 256, 0, stream>>>(Q, P, lsum);
  // 4) out = (P~ V)/lsum.  TM=128, BK=128 (halved barriers at res-2), 512 blocks.
  pv_k<<<dim3(128, 1, 4), 256, 0, stream>>>(P, Vt, out, lsum);
}